// Round 5
// baseline (11040.332 us; speedup 1.0000x reference)
//
#include <hip/hip_runtime.h>

// LSTM_3813930958978: T=512, B=64, I=1024, H=1024, gate order i,f,g,o.
// Persistent cooperative kernel, 64 blocks x 512 threads (1 block/CU).
// Block k owns h-columns [16k, 16k+16) => 64 gate columns.
// Waves 0-3: x_t @ W_ih^T (never wait on the barrier).
// Waves 4-7: poll relay, threadfence (acquire), h @ W_hh^T.
// Wave j (within part): colhalf = j&1 (32 of the 64 gate cols),
// khalf = j>>1 (512 of 1024 K). 32 register B-frags per wave (128 VGPR).
// Sync protocol = R2's (best measured): plain h loads + threadfence
// acquire after poll; release threadfence + 2-level arrival tree
// (8 leaves x 8 blocks -> root x 8) + relay fan-out in tid0.

#define TT 512
#define BB 64
#define II 1024
#define HHH 1024
#define G4 4096
#define NBLK 64
#define HPB 16           // h-columns per block
#define NTHR 512

typedef __attribute__((ext_vector_type(8))) short short8;
typedef __attribute__((ext_vector_type(4))) float f32x4;
typedef __attribute__((ext_vector_type(4))) int i32x4;

__device__ __forceinline__ short8 load_frag(const unsigned short* p) {
  i32x4 v = *(const i32x4*)p;
  return __builtin_bit_cast(short8, v);
}

__device__ __forceinline__ unsigned short f2bf(float f) {  // full RTN
  unsigned u = __builtin_bit_cast(unsigned, f);
  u = (u + 0x7FFFu + ((u >> 16) & 1u)) >> 16;
  return (unsigned short)u;
}

__device__ __forceinline__ float sigm(float x) {
  return 1.0f / (1.0f + __expf(-x));
}
__device__ __forceinline__ float tanh_f(float x) {
  return 2.0f / (1.0f + __expf(-2.0f * x)) - 1.0f;
}

// ---- conversion kernels ------------------------------------------------
__global__ void cvt_bf16(const float* __restrict__ s,
                         unsigned short* __restrict__ d, int n4) {
  int stride = gridDim.x * blockDim.x;
  for (int i = blockIdx.x * blockDim.x + threadIdx.x; i < n4; i += stride) {
    f32x4 v = *(const f32x4*)(s + 4 * i);
    unsigned lo = (unsigned)f2bf(v[0]) | ((unsigned)f2bf(v[1]) << 16);
    unsigned hi = (unsigned)f2bf(v[2]) | ((unsigned)f2bf(v[3]) << 16);
    uint2 u; u.x = lo; u.y = hi;
    *(uint2*)(d + 4 * i) = u;
  }
}

__global__ void bias_sum(const float* __restrict__ a,
                         const float* __restrict__ b,
                         float* __restrict__ o) {
  int i = blockIdx.x * blockDim.x + threadIdx.x;
  if (i < G4) o[i] = a[i] + b[i];
}

// ---- persistent LSTM kernel -------------------------------------------
// barrier_mem (uint words, 128B-spaced):
//   [0]              root counter
//   [32*(1+g)]       relay line g (g=0..7)  -- polled, written by winner
//   [32*(9+g)]       leaf counter g (g=0..7)
__global__ __launch_bounds__(NTHR, 1) void lstm_persist(
    const unsigned short* __restrict__ xb,    // [T][64][1024] bf16
    const unsigned short* __restrict__ wih,   // [4096][1024] bf16
    const unsigned short* __restrict__ whh,   // [4096][1024] bf16
    const float* __restrict__ bsum,           // [4096] f32 (b_ih + b_hh)
    unsigned short* __restrict__ hbuf,        // 2 x [64][1024] bf16
    unsigned int* __restrict__ barrier_mem,   // zeroed
    float* __restrict__ out)                  // [64][1024] f32
{
  const int tid = threadIdx.x;
  const int wid = tid >> 6;          // wave 0..7
  const int lane = tid & 63;
  const int ln15 = lane & 15;
  const int quad = lane >> 4;
  const int hc0 = blockIdx.x * HPB;  // this block's first h-column
  const bool isx = (wid < 4);        // waves 0-3: x part; 4-7: h part
  const int j = wid & 3;
  const int ch = j & 1;              // colhalf: 32 of 64 gate cols
  const int koff = (j >> 1) * 512;   // K-half
  const unsigned short* wsrc = isx ? wih : whh;
  const int grp = blockIdx.x >> 3;   // barrier group 0..7 (8 blocks each)

  unsigned int* root = barrier_mem;
  unsigned int* relay = barrier_mem + 32 * (1 + grp);
  unsigned int* leaf = barrier_mem + 32 * (9 + grp);

  __shared__ float red[8][64][36];   // 73.7 KiB; each wave writes cols [0,32)

  // ---- load persistent B fragments (weights) --------------------------
  // Block gate-col cc in [0,64): gate q = cc>>4, h-col r = cc&15
  //   -> weight row = q*1024 + hc0 + r.
  // Wave covers cc = ch*32 + nt*16 + ln15 (nt=0,1), K = koff + kc*32 + quad*8.
  short8 bfrag[16][2];
#pragma unroll
  for (int nt = 0; nt < 2; ++nt) {
    int cc = ch * 32 + nt * 16 + ln15;
    int grow = (cc >> 4) * 1024 + hc0 + (cc & 15);
#pragma unroll
    for (int kc = 0; kc < 16; ++kc) {
      int k = koff + kc * 32 + quad * 8;
      bfrag[kc][nt] = load_frag(wsrc + grow * 1024 + k);
    }
  }

  // ---- elementwise-phase constants ------------------------------------
  const int eb = tid >> 3;   // batch row (64 rows, 8 threads each)
  const int erp = tid & 7;   // handles h-cols hc0 + erp*2 + {0,1}
  float bsv[4][2];
#pragma unroll
  for (int q = 0; q < 4; ++q)
#pragma unroll
    for (int rr = 0; rr < 2; ++rr)
      bsv[q][rr] = bsum[q * 1024 + hc0 + erp * 2 + rr];

  float cst[2] = {0.0f, 0.0f};  // c-state, fp32, lives in registers

#pragma unroll 1
  for (int t = 0; t < TT; ++t) {
    const unsigned short* hsrc = hbuf + (t & 1) * (BB * HHH);
    unsigned short* hdst = hbuf + ((t + 1) & 1) * (BB * HHH);

    f32x4 acc[4][2];
#pragma unroll
    for (int m = 0; m < 4; ++m)
#pragma unroll
      for (int nt = 0; nt < 2; ++nt)
        acc[m][nt] = (f32x4){0.0f, 0.0f, 0.0f, 0.0f};

    // ---- phase A: per-wave GEMM partials (registers only) -------------
    const unsigned short* asrc = nullptr;
    if (isx) {
      asrc = xb + (size_t)t * (BB * II);   // no global wait for x-waves
    } else if (t > 0) {
      // h-waves: poll this group's relay line (read-only, s_sleep
      // backoff), then acquire-fence and plain loads (R2 protocol).
      while (__hip_atomic_load(relay, __ATOMIC_RELAXED,
                               __HIP_MEMORY_SCOPE_AGENT) < (unsigned)t)
        __builtin_amdgcn_s_sleep(1);
      __threadfence();   // acquire: invalidate stale cached h lines
      asrc = hsrc;
    }

    if (asrc) {
#pragma unroll
      for (int kc = 0; kc < 16; ++kc) {
        int k = koff + kc * 32 + quad * 8;
#pragma unroll
        for (int m = 0; m < 4; ++m) {
          short8 a = load_frag(asrc + (m * 16 + ln15) * 1024 + k);
          acc[m][0] = __builtin_amdgcn_mfma_f32_16x16x32_bf16(
              a, bfrag[kc][0], acc[m][0], 0, 0, 0);
          acc[m][1] = __builtin_amdgcn_mfma_f32_16x16x32_bf16(
              a, bfrag[kc][1], acc[m][1], 0, 0, 0);
        }
      }
    }
    // (h-waves at t==0: h0 = 0 -> partials stay zero, no loads)

    // ---- dump partials to LDS (D layout: row=(quad*4+p), col=ln15) ----
#pragma unroll
    for (int m = 0; m < 4; ++m)
#pragma unroll
      for (int nt = 0; nt < 2; ++nt)
#pragma unroll
        for (int p = 0; p < 4; ++p)
          red[wid][m * 16 + quad * 4 + p][nt * 16 + ln15] = acc[m][nt][p];

    __syncthreads();   // (#1)

    // ---- reduce 4 partials + bias, gate nonlinearities, state update --
    // Target gate-col cc = q*16 + r_local; colhalf c2 = cc>>5; local col
    // lc = cc&31. Summands: x-waves {c2, 2+c2}, h-waves {4+c2, 6+c2}.
    float hv[2];
#pragma unroll
    for (int rr = 0; rr < 2; ++rr) {
      int r = erp * 2 + rr;            // h-col within block, 0..15
      float g[4];
#pragma unroll
      for (int q = 0; q < 4; ++q) {
        int cc = q * 16 + r;
        int c2 = cc >> 5;
        int lc = cc & 31;
        g[q] = red[c2][eb][lc] + red[2 + c2][eb][lc] + red[4 + c2][eb][lc] +
               red[6 + c2][eb][lc] + bsv[q][rr];
      }
      float ig = sigm(g[0]);
      float fg = sigm(g[1]);
      float gg = tanh_f(g[2]);
      float og = sigm(g[3]);
      float c = fg * cst[rr] + ig * gg;
      cst[rr] = c;
      hv[rr] = og * tanh_f(c);
    }
    unsigned hpack = (unsigned)f2bf(hv[0]) | ((unsigned)f2bf(hv[1]) << 16);
    *(unsigned*)(hdst + eb * HHH + hc0 + erp * 2) = hpack;

    if (t == TT - 1) {
      float2 o2; o2.x = hv[0]; o2.y = hv[1];
      *(float2*)(out + eb * HHH + hc0 + erp * 2) = o2;
    }

    __syncthreads();   // (#2) all h stores vmcnt-drained by every thread

    // ---- arrival: release fence + 2-level tree + relay fan-out --------
    if (t < TT - 1 && tid == 0) {
      __threadfence();   // release: flush this block's h writes device-wide
      unsigned old = atomicAdd(leaf, 1u);
      if (old == (unsigned)t * 8u + 7u) {          // last of 8 in group
        unsigned old2 = atomicAdd(root, 1u);
        if (old2 == (unsigned)t * 8u + 7u) {       // last of 8 groups
#pragma unroll
          for (int g = 0; g < 8; ++g)              // fan out to 8 lines
            __hip_atomic_store(barrier_mem + 32 * (1 + g), (unsigned)(t + 1),
                               __ATOMIC_RELAXED, __HIP_MEMORY_SCOPE_AGENT);
        }
      }
    }
    // x-waves fall through to step t+1 immediately; h-waves poll there.
  }
}

// ---- launcher ----------------------------------------------------------
extern "C" void kernel_launch(void* const* d_in, const int* in_sizes, int n_in,
                              void* d_out, int out_size, void* d_ws,
                              size_t ws_size, hipStream_t stream) {
  (void)in_sizes; (void)n_in; (void)out_size; (void)ws_size;
  const float* x   = (const float*)d_in[0];
  const float* wih = (const float*)d_in[1];
  const float* whh = (const float*)d_in[2];
  const float* bih = (const float*)d_in[3];
  const float* bhh = (const float*)d_in[4];

  char* ws = (char*)d_ws;
  // workspace layout (bytes):
  //   [0, 4096)          barrier: root/relay/leaf lines (128B-spaced)
  //   [4096, +256KiB)    h double buffer (2 x 64x1024 bf16)
  //   [1MiB, 9MiB)       W_ih bf16
  //   [9MiB, 17MiB)      W_hh bf16
  //   [17MiB, +16KiB)    bias sum f32
  //   [18MiB, 82MiB)     x bf16
  unsigned int*   bar  = (unsigned int*)(ws);
  unsigned short* hb   = (unsigned short*)(ws + 4096);
  unsigned short* wihb = (unsigned short*)(ws + (1ull << 20));
  unsigned short* whhb = (unsigned short*)(ws + (9ull << 20));
  float*          bs   = (float*)(ws + (17ull << 20));
  unsigned short* xb   = (unsigned short*)(ws + (18ull << 20));

  // zero the barrier area (ws is poisoned 0xAA before every launch).
  // h buffer needs no init: slot read at t=0 is skipped (h0 = 0).
  hipMemsetAsync(ws, 0, 4096, stream);

  cvt_bf16<<<2048, 256, 0, stream>>>(x, xb, (TT * BB * II) / 4);
  cvt_bf16<<<1024, 256, 0, stream>>>(wih, wihb, (G4 * II) / 4);
  cvt_bf16<<<1024, 256, 0, stream>>>(whh, whhb, (G4 * HHH) / 4);
  bias_sum<<<16, 256, 0, stream>>>(bih, bhh, bs);

  lstm_persist<<<NBLK, NTHR, 0, stream>>>(xb, wihb, whhb, bs, hb, bar,
                                          (float*)d_out);
}